// Round 10
// baseline (564.960 us; speedup 1.0000x reference)
//
#include <hip/hip_runtime.h>

#define S_LEN 2048
#define BATCH 2
#define HID 4096
#define NH 32
#define NKV 8
#define DH 128
#define MROWS (BATCH*S_LEN)   // 4096
#define QKV_N 6144

typedef unsigned short u16;
typedef unsigned int u32;
typedef __bf16 bf16x8 __attribute__((ext_vector_type(8)));
typedef float f32x4 __attribute__((ext_vector_type(4)));
typedef u16 u16x8 __attribute__((ext_vector_type(8)));

__device__ __forceinline__ u16 f2bf(float f) {           // round-half-up (2 insts)
  union { float f; u32 u; } v; v.f = f;
  return (u16)((v.u + 0x8000u) >> 16);
}
__device__ __forceinline__ float bf2f(u16 h) {
  union { u32 u; float f; } v; v.u = ((u32)h) << 16;
  return v.f;
}
__device__ __forceinline__ u32 cvtpk(float a, float b) { // packs bf16(a)|bf16(b)<<16
  u32 r;
  asm("v_cvt_pk_bf16_f32 %0, %1, %2" : "=v"(r) : "v"(a), "v"(b));
  return r;
}
__device__ __forceinline__ void async16(const void* g, void* l) {
  __builtin_amdgcn_global_load_lds(
      (const __attribute__((address_space(1))) u32*)g,
      (__attribute__((address_space(3))) u32*)l, 16, 0, 0);
}
__device__ __forceinline__ f32x4 mfma16(bf16x8 a, bf16x8 b, f32x4 c) {
  return __builtin_amdgcn_mfma_f32_16x16x32_bf16(a, b, c, 0, 0, 0);
}

// ---------------- fp32 -> bf16 conversion ----------------
__global__ __launch_bounds__(256) void cvt_f32_bf16(const float* __restrict__ in,
                                                    u16* __restrict__ out, int n) {
  int i0 = (blockIdx.x * 256 + threadIdx.x) * 8;
  if (i0 >= n) return;
  float4 a = *(const float4*)(in + i0);
  float4 b = *(const float4*)(in + i0 + 4);
  u16x8 r;
  r[0]=f2bf(a.x); r[1]=f2bf(a.y); r[2]=f2bf(a.z); r[3]=f2bf(a.w);
  r[4]=f2bf(b.x); r[5]=f2bf(b.y); r[6]=f2bf(b.z); r[7]=f2bf(b.w);
  *(u16x8*)(out + i0) = r;
}

// ---------------- 128x128 NT bf16 GEMM, r10: 2 blocks/CU co-residency ------
// r5-r9 (256x256, 128KB LDS) pinned at ~240us regardless of fetch (362->175MB),
// FLOPs (206 vs 137GF), conflicts (0), vmcnt schedule: the wall is same-block
// barrier lockstep with exactly 1 block/CU -- every wait is CU-wide dead time,
// no independent wave fills bubbles (Guideline 1; r3's multi-block/CU kernel
// hit 750TF with a weaker schedule).
// This kernel: 128x128 tile, BK=64, 4 waves (2x2), per-wave C=64x64; LDS 64KB
// -> 2 independent blocks/CU. Schedule keeps r7's levers: read-ahead regs,
// counted vmcnt(8) (never 0), full 3-bit chunk swizzle (0 conflicts), setprio,
// wait-then-barrier for cross-wave DMA landing.
// Per K-tile (2 phases, 4 barriers):
//  P1: rd bfR(c) | bar1 | MFMA(af x bfL -> nf0-1) | bar2
//  P2: stage A(k+2),B(k+2)->buf c | bar3 | MFMA(af x bfR -> nf2-3) | vmcnt(8)
//      | bar4 | rd af(c^1), bfL(c^1)
// vmcnt(8) drains A(k+1),B(k+1) (issued P2(k-1), >=2 phases old); bar4 then
// guarantees all waves' loads landed before the c^1 reads. Stage->buf c at P2
// is >=1 barrier past forced consumption of buf c's last ds_reads (ledger ok).
template<int OUT_BF16>
__global__ __launch_bounds__(256, 2) void gemm128(
    const u16* __restrict__ A, const u16* __restrict__ B, void* __restrict__ Cout,
    int M, int N, int K, int XC, int SR, int SC) {
  __shared__ u16 As[2][128 * 64];      // [dbuf][128 rows x 64 cols]
  __shared__ u16 Bs[2][128 * 64];
  const int NKT = K >> 6;              // K-tiles of 64 (requires NKT >= 4)
  int bid = (int)blockIdx.x;
  int xcd = bid & 7, l = bid >> 3;     // 2-D XCD sub-grid map (r9, kept)
  int tm = (xcd / XC) * SR + l / SC;
  int tn = (xcd % XC) * SC + l % SC;
  int m0 = tm << 7, n0 = tn << 7;
  int t = threadIdx.x;
  int w = t >> 6, lane = t & 63, lo = lane & 15, hi = lane >> 4;
  int wm = w >> 1, wn = w & 1;

  int srow_t = t >> 3;                 // staging row within 32-row group
  int schunk = t & 7;                  // 16B chunk within 128B row

  auto stageA = [&](int kt, int buf) {
#pragma unroll
    for (int r = 0; r < 4; ++r) {
      int row = (r << 5) + srow_t;
      int src = schunk ^ (row & 7);    // inverse swizzle on global source
      async16(A + (size_t)(m0 + row) * K + (kt << 6) + src * 8,
              (char*)&As[buf][0] + (r << 12) + (w << 10));
    }
  };
  auto stageB = [&](int kt, int buf) {
#pragma unroll
    for (int r = 0; r < 4; ++r) {
      int row = (r << 5) + srow_t;
      int src = schunk ^ (row & 7);
      async16(B + (size_t)(n0 + row) * K + (kt << 6) + src * 8,
              (char*)&Bs[buf][0] + (r << 12) + (w << 10));
    }
  };

  const f32x4 fz = {0.f, 0.f, 0.f, 0.f};
  f32x4 acc[4][4];
#pragma unroll
  for (int i = 0; i < 4; ++i)
#pragma unroll
    for (int j = 0; j < 4; ++j) acc[i][j] = fz;
  bf16x8 af[4][2], bfL[2][2], bfR[2][2];

  auto rdA = [&](int c, bf16x8 (&dst)[4][2]) {             // 8 x ds_read_b128
    const u16* Ab = &As[c][0];
#pragma unroll
    for (int mf = 0; mf < 4; ++mf)
#pragma unroll
      for (int ks = 0; ks < 2; ++ks) {
        int ra = (wm << 6) + (mf << 4) + lo;
        dst[mf][ks] = *(const bf16x8*)(Ab + ra * 64 +
                      ((((ks << 2) + hi) ^ (ra & 7)) << 3));
      }
  };
  auto rdBh = [&](int c, int half, bf16x8 (&dst)[2][2]) {  // 4 x ds_read_b128
    const u16* Bb = &Bs[c][0];
#pragma unroll
    for (int nf = 0; nf < 2; ++nf)
#pragma unroll
      for (int ks = 0; ks < 2; ++ks) {
        int rb = (wn << 6) + (half << 5) + (nf << 4) + lo;
        dst[nf][ks] = *(const bf16x8*)(Bb + rb * 64 +
                      ((((ks << 2) + hi) ^ (rb & 7)) << 3));
      }
  };
  auto MM = [&](bf16x8 (&a)[4][2], bf16x8 (&b)[2][2], int no) {  // 16 MFMA
#pragma unroll
    for (int mf = 0; mf < 4; ++mf)
#pragma unroll
      for (int nf = 0; nf < 2; ++nf)
#pragma unroll
        for (int ks = 0; ks < 2; ++ks)
          acc[mf][no + nf] = mfma16(a[mf][ks], b[nf][ks], acc[mf][no + nf]);
  };

  // prologue: stage tiles 0,1 fully; drain tile0 (8 oldest), keep tile1 flying
  stageA(0, 0); stageB(0, 0);
  stageA(1, 1); stageB(1, 1);
  asm volatile("s_waitcnt vmcnt(8)" ::: "memory");
  __builtin_amdgcn_s_barrier();
  rdA(0, af);
  rdBh(0, 0, bfL);

  for (int kt = 0; kt < NKT; ++kt) {
    int c = kt & 1;
    int kn2 = kt + 2; if (kn2 >= NKT) kn2 -= NKT;   // wrap: redundant but uniform

    // ---- P1: read bfR(c); MFMA left half (nf0-1)
    rdBh(c, 1, bfR);
    __builtin_amdgcn_s_barrier();                   // bar1
    __builtin_amdgcn_s_setprio(1);
    MM(af, bfL, 0);
    __builtin_amdgcn_s_setprio(0);
    __builtin_amdgcn_s_barrier();                   // bar2

    // ---- P2: stage tile k+2 -> buf c; MFMA right half (nf2-3); counted vmcnt
    stageA(kn2, c); stageB(kn2, c);
    __builtin_amdgcn_s_barrier();                   // bar3
    __builtin_amdgcn_s_setprio(1);
    MM(af, bfR, 2);
    __builtin_amdgcn_s_setprio(0);
    asm volatile("s_waitcnt vmcnt(8)" ::: "memory"); // drains A(k+1),B(k+1)
    __builtin_amdgcn_s_barrier();                   // bar4: all waves' loads landed
    rdA(c ^ 1, af);                                  // feeds next iteration
    rdBh(c ^ 1, 0, bfL);
  }

  // epilogue
#pragma unroll
  for (int mf = 0; mf < 4; ++mf)
#pragma unroll
    for (int nf = 0; nf < 4; ++nf)
#pragma unroll
      for (int r = 0; r < 4; ++r) {
        int row = m0 + (wm << 6) + (mf << 4) + (hi << 2) + r;
        int col = n0 + (wn << 6) + (nf << 4) + lo;
        if (OUT_BF16) ((u16*)Cout)[(size_t)row * N + col] = f2bf(acc[mf][nf][r]);
        else          ((float*)Cout)[(size_t)row * N + col] = acc[mf][nf][r];
      }
}

// ---------------- RoPE (in-place on bf16, optional output scale) ----------------
__global__ __launch_bounds__(256) void rope_kernel(u16* __restrict__ X,
                                                   const int* __restrict__ pos,
                                                   int ncols, int pitch, float scale) {
  int idx = blockIdx.x * 256 + threadIdx.x;
  int groups = ncols >> 3;
  int m = idx / groups;
  int gi = idx - m * groups;
  if (m >= MROWS) return;
  int head = gi >> 4;
  int d0 = (gi & 15) << 2;
  float p = (float)pos[m];
  u16* base = X + (size_t)m * pitch + head * 128;
  u16 xa[4], xb[4], oa[4], ob[4];
  *(uint2*)xa = *(const uint2*)(base + d0);
  *(uint2*)xb = *(const uint2*)(base + d0 + 64);
#pragma unroll
  for (int i = 0; i < 4; ++i) {
    float j = (float)(d0 + i);
    float inv = __expf(j * -0.14391156516030342f);  // ln(10000)/64
    float fr = p * inv;
    float s, c;
    sincosf(fr, &s, &c);
    float x1 = bf2f(xa[i]), x2 = bf2f(xb[i]);
    oa[i] = f2bf((x1 * c - x2 * s) * scale);
    ob[i] = f2bf((x2 * c + x1 * s) * scale);
  }
  *(uint2*)(base + d0) = *(uint2*)oa;
  *(uint2*)(base + d0 + 64) = *(uint2*)ob;
}

// ---------------- V transpose: QKV[m][5120 + g*128 + d] -> Vt[(b*8+g)*128 + d][s] ----------------
__global__ __launch_bounds__(256) void transpose_v(const u16* __restrict__ V,
                                                   u16* __restrict__ Vt) {
  int bid = blockIdx.x;
  int s0 = (bid & 31) << 6;
  int bg = bid >> 5;
  int b = bg >> 3, g = bg & 7;
  __shared__ u16 tile[64][128];
  int t = threadIdx.x;
#pragma unroll
  for (int r = 0; r < 4; ++r) {
    int c = (r << 8) + t;
    int row = c >> 4, cc = c & 15;
    *(uint4*)&tile[row][cc * 8] =
        *(const uint4*)(V + (size_t)(b * S_LEN + s0 + row) * QKV_N + g * 128 + cc * 8);
  }
  __syncthreads();
#pragma unroll
  for (int r = 0; r < 4; ++r) {
    int c = (r << 8) + t;
    int d = c >> 3, cs = c & 7;
    u16 tmp[8];
#pragma unroll
    for (int i = 0; i < 8; ++i) tmp[i] = tile[cs * 8 + i][d];
    *(uint4*)(Vt + ((size_t)bg * 128 + d) * S_LEN + s0 + cs * 8) = *(uint4*)tmp;
  }
}

// ---------------- Flash attention (causal, GQA 4:1), swapped-operand layout ----------------
__global__ __launch_bounds__(256) void attn_kernel(
    const u16* __restrict__ Q, const u16* __restrict__ K,
    const u16* __restrict__ Vt, u16* __restrict__ O) {
  int bid = blockIdx.x;
  int qt = 31 - (bid >> 6);          // heavy tiles first
  int bh = bid & 63;
  int b = bh >> 5, h = bh & 31;
  int g = h >> 2;
  __shared__ u16 Kl[64 * 128];
  __shared__ u16 Vl[128 * 64];
  __shared__ u16 Pl[4][16 * 72];     // per-wave P^T / O-bounce, pitch 72
  int t = threadIdx.x, w = t >> 6, lane = t & 63, lo = lane & 15, hi = lane >> 4;

  bf16x8 qf[4];   // B-operand: lane -> Q row (q=lo)
  {
    const u16* qb = Q + (size_t)(b * S_LEN + (qt << 6) + (w << 4) + lo) * QKV_N + h * 128;
#pragma unroll
    for (int kk = 0; kk < 4; ++kk) qf[kk] = *(const bf16x8*)(qb + kk * 32 + hi * 8);
  }
  const f32x4 fz = {0.f, 0.f, 0.f, 0.f};
  f32x4 acc[8];
#pragma unroll
  for (int f = 0; f < 8; ++f) acc[f] = fz;
  float mrun = -1e30f, lrun = 0.f;

  const u16* Kbase = K + (size_t)(b * S_LEN) * QKV_N + g * 128;
  const u16* Vbase = Vt + (size_t)((b << 3) + g) * 128 * S_LEN;

  int ntiles = qt + 1;
  for (int tile = 0; tile < ntiles; ++tile) {
    int s0 = tile << 6;
#pragma unroll
    for (int r = 0; r < 4; ++r) {              // stage K tile [64][128], chunk-swizzled
      int c = (r << 8) + (w << 6) + lane;
      int row = c >> 4, cc = c & 15;
      int src = cc ^ (row & 7);
      async16(Kbase + (size_t)(s0 + row) * QKV_N + src * 8,
              (char*)Kl + (r << 12) + (w << 10));
    }
#pragma unroll
    for (int r = 0; r < 4; ++r) {              // stage V^T tile [128][64], chunk-swizzled
      int c = (r << 8) + (w << 6) + lane;
      int row = c >> 3, cc = c & 7;
      int src = cc ^ (row & 7);
      async16(Vbase + (size_t)row * S_LEN + s0 + src * 8,
              (char*)Vl + (r << 12) + (w << 10));
    }
    __syncthreads();

    f32x4 sf[4];
#pragma unroll
    for (int j = 0; j < 4; ++j) {
      f32x4 sv = fz;
#pragma unroll
      for (int kk = 0; kk < 4; ++kk) {
        int row = (j << 4) + lo;
        int ch = ((kk << 2) + hi) ^ (row & 7);
        bf16x8 kf = *(const bf16x8*)(Kl + row * 128 + ch * 8);
        sv = __builtin_amdgcn_mfma_f32_16x16x32_bf16(kf, qf[kk], sv, 0, 0, 0);
      }
      sf[j] = sv;
    }
    if (tile == qt) {                           // causal mask on diagonal tile
      int q_rel = (w << 4) + lo;
#pragma unroll
      for (int j = 0; j < 4; ++j)
#pragma unroll
        for (int r = 0; r < 4; ++r)
          if (((j << 4) + (hi << 2) + r) > q_rel) sf[j][r] = -1e9f;
    }
    float pmax = sf[0][0];
#pragma unroll
    for (int j = 0; j < 4; ++j)
#pragma unroll
      for (int r = 0; r < 4; ++r) pmax = fmaxf(pmax, sf[j][r]);
    pmax = fmaxf(pmax, __shfl_xor(pmax, 16, 64));
    pmax = fmaxf(pmax, __shfl_xor(pmax, 32, 64));
    if (__any(pmax > mrun + 8.f)) {             // defer-max rescale (THR=8)
      float mn = fmaxf(mrun, pmax);
      float fsc = __expf(mrun - mn);
      mrun = mn;
      lrun *= fsc;
#pragma unroll
      for (int f = 0; f < 8; ++f)
#pragma unroll
        for (int r = 0; r < 4; ++r) acc[f][r] *= fsc;
    }
    float psum = 0.f;
#pragma unroll
    for (int j = 0; j < 4; ++j)
#pragma unroll
      for (int r = 0; r < 4; ++r) {
        float p = __expf(sf[j][r] - mrun);
        sf[j][r] = p;
        psum += p;
      }
    psum += __shfl_xor(psum, 16, 64);
    psum += __shfl_xor(psum, 32, 64);
    lrun += psum;

#pragma unroll
    for (int j = 0; j < 4; ++j) {
      uint2 pk;
      pk.x = cvtpk(sf[j][0], sf[j][1]);
      pk.y = cvtpk(sf[j][2], sf[j][3]);
      *(uint2*)&Pl[w][lo * 72 + (j << 4) + (hi << 2)] = pk;
    }
#pragma unroll
    for (int kk = 0; kk < 2; ++kk) {
      bf16x8 pf = *(const bf16x8*)&Pl[w][lo * 72 + (kk << 5) + (hi << 3)];
#pragma unroll
      for (int f = 0; f < 8; ++f) {
        int vrow = (f << 4) + lo;
        int phys = ((kk << 2) + hi) ^ (vrow & 7);
        bf16x8 vf = *(const bf16x8*)(Vl + vrow * 64 + phys * 8);
        acc[f] = __builtin_amdgcn_mfma_f32_16x16x32_bf16(vf, pf, acc[f], 0, 0, 0);
      }
    }
    __syncthreads();
  }

  float rl = 1.0f / lrun;
#pragma unroll
  for (int half = 0; half < 2; ++half) {
#pragma unroll
    for (int f2 = 0; f2 < 4; ++f2) {
      int f = (half << 2) + f2;
      uint2 pk;
      pk.x = cvtpk(acc[f][0] * rl, acc[f][1] * rl);
      pk.y = cvtpk(acc[f][2] * rl, acc[f][3] * rl);
      *(uint2*)&Pl[w][lo * 72 + (f2 << 4) + (hi << 2)] = pk;
    }
#pragma unroll
    for (int it = 0; it < 2; ++it) {
      int rowq = (lane >> 3) + (it << 3);
      int c8 = lane & 7;
      uint4 val = *(const uint4*)&Pl[w][rowq * 72 + c8 * 8];
      *(uint4*)(O + (size_t)(b * S_LEN + (qt << 6) + (w << 4) + rowq) * 4096 +
                h * 128 + (half << 6) + c8 * 8) = val;
    }
  }
}

// ---------------- launch ----------------
extern "C" void kernel_launch(void* const* d_in, const int* in_sizes, int n_in,
                              void* d_out, int out_size, void* d_ws, size_t ws_size,
                              hipStream_t stream) {
  const float* hidden = (const float*)d_in[0];
  const int* pos = (const int*)d_in[1];
  const float* Wq = (const float*)d_in[2];
  const float* Wk = (const float*)d_in[3];
  const float* Wv = (const float*)d_in[4];
  const float* Wo = (const float*)d_in[5];
  float* out = (float*)d_out;

  u16* hb   = (u16*)d_ws;                 // [4096][4096]
  u16* wqb  = hb   + 16777216;            // [4096][4096]  } contiguous -> fused
  u16* wkb  = wqb  + 16777216;            // [1024][4096]  }   B matrix [6144][4096]
  u16* wvb  = wkb  + 4194304;             // [1024][4096]  }
  u16* wob  = wvb  + 4194304;             // [4096][4096]
  u16* QKVb = wob  + 16777216;            // [4096][6144]
  u16* Vtb  = QKVb + 25165824;            // [16*128][2048]
  u16* Ob   = Vtb  + 4194304;             // [4096][4096]

  cvt_f32_bf16<<<8192, 256, 0, stream>>>(hidden, hb, 16777216);
  cvt_f32_bf16<<<8192, 256, 0, stream>>>(Wq, wqb, 16777216);
  cvt_f32_bf16<<<2048, 256, 0, stream>>>(Wk, wkb, 4194304);
  cvt_f32_bf16<<<2048, 256, 0, stream>>>(Wv, wvb, 4194304);
  cvt_f32_bf16<<<8192, 256, 0, stream>>>(Wo, wob, 16777216);

  // QKV: 32x48 tiles = 1536 blocks; XCD-grid 2x4, sub 16x12 (XC=4,SR=16,SC=12)
  gemm128<1><<<1536, 256, 0, stream>>>(hb, wqb, QKVb, 4096, QKV_N, 4096, 4, 16, 12);

  rope_kernel<<<8192, 256, 0, stream>>>(QKVb, pos, 4096, QKV_N, 0.08838834764831845f); // Q (pre-scaled)
  rope_kernel<<<2048, 256, 0, stream>>>(QKVb + 4096, pos, 1024, QKV_N, 1.0f);          // K

  transpose_v<<<512, 256, 0, stream>>>(QKVb + 5120, Vtb);

  attn_kernel<<<2048, 256, 0, stream>>>(QKVb, QKVb + 4096, Vtb, Ob);

  // O-proj: 32x32 tiles = 1024 blocks; XCD-grid 4x2, sub 8x16 (XC=2,SR=8,SC=16)
  gemm128<0><<<1024, 256, 0, stream>>>(Ob, wob, out, 4096, 4096, 4096, 2, 8, 16);
}

// Round 11
// 539.306 us; speedup vs baseline: 1.0476x; 1.0476x over previous
//
#include <hip/hip_runtime.h>

#define S_LEN 2048
#define BATCH 2
#define HID 4096
#define NH 32
#define NKV 8
#define DH 128
#define MROWS (BATCH*S_LEN)   // 4096
#define QKV_N 6144

typedef unsigned short u16;
typedef unsigned int u32;
typedef __bf16 bf16x8 __attribute__((ext_vector_type(8)));
typedef float f32x4 __attribute__((ext_vector_type(4)));
typedef u16 u16x8 __attribute__((ext_vector_type(8)));

__device__ __forceinline__ u16 f2bf(float f) {           // round-half-up (2 insts)
  union { float f; u32 u; } v; v.f = f;
  return (u16)((v.u + 0x8000u) >> 16);
}
__device__ __forceinline__ float bf2f(u16 h) {
  union { u32 u; float f; } v; v.u = ((u32)h) << 16;
  return v.f;
}
__device__ __forceinline__ u32 cvtpk(float a, float b) { // packs bf16(a)|bf16(b)<<16
  u32 r;
  asm("v_cvt_pk_bf16_f32 %0, %1, %2" : "=v"(r) : "v"(a), "v"(b));
  return r;
}
__device__ __forceinline__ void async16(const void* g, void* l) {
  __builtin_amdgcn_global_load_lds(
      (const __attribute__((address_space(1))) u32*)g,
      (__attribute__((address_space(3))) u32*)l, 16, 0, 0);
}
__device__ __forceinline__ f32x4 mfma16(bf16x8 a, bf16x8 b, f32x4 c) {
  return __builtin_amdgcn_mfma_f32_16x16x32_bf16(a, b, c, 0, 0, 0);
}

// ---------------- fp32 -> bf16 conversion ----------------
__global__ __launch_bounds__(256) void cvt_f32_bf16(const float* __restrict__ in,
                                                    u16* __restrict__ out, int n) {
  int i0 = (blockIdx.x * 256 + threadIdx.x) * 8;
  if (i0 >= n) return;
  float4 a = *(const float4*)(in + i0);
  float4 b = *(const float4*)(in + i0 + 4);
  u16x8 r;
  r[0]=f2bf(a.x); r[1]=f2bf(a.y); r[2]=f2bf(a.z); r[3]=f2bf(a.w);
  r[4]=f2bf(b.x); r[5]=f2bf(b.y); r[6]=f2bf(b.z); r[7]=f2bf(b.w);
  *(u16x8*)(out + i0) = r;
}

// ---------------- 256x256 NT bf16 GEMM, r11: faithful m201 8-phase port ----
// 512 thr = 8 waves (2M x 4N); BK=64; per-wave C = 128x64 (8x4 frags 16x16).
// LDS 128KB [dbuf2][half2][128x64]; 3-bit chunk swizzle (0 conflicts, r5);
// 2-D XCD sub-grid map (r9).
// r11 change (the lever m196 A/B isolated): ds_reads IN-PHASE, immediately
// before their consuming MFMA: {reads | 1 stage-unit -> bar -> lgkmcnt(0) ->
// setprio(1) -> 16 MFMA -> setprio(0) -> bar}. Buffers parity-fixed
// (buf0=even K-tiles, buf1=odd). 8 phases per 2 K-tiles:
//  P1: rdA0,rdB0(e)[12] | stg A(o).h0 | Q00   P5: same on o | stg A(e+2).h0 | Q00
//  P2: rdB1(e)[4]       | stg A(o).h1 | Q01   P6:           | stg A(e+2).h1 | Q01
//  P3: rdA1(e)[8]       | stg B(e+2).h0 | Q11 P7:           | stg B(o+2).h0 | Q11
//  P4:                  | stg B(e+2).h1 | Q10,vmcnt(4)
//                                             P8:           | stg B(o+2).h1 | Q10,vmcnt(4)
// Stage units = LDS regions As/Bs[buf][h] (2 gloads each). Ledger (verified):
// every stage >=1 barrier after its region's last read (A[buf] read P1&P3 ->
// restage P5+; B[buf] read P1&P2 -> restage P3+; odd A restaged P1-P2 next
// pair); vmcnt(4)@P4 drains A(o)[P1,P2] + B(o)[P7,P8 prev] before P5-P7 reads;
// vmcnt(4)@P8 drains A(e+2)[P5,P6] + B(e+2)[P3,P4] before next P1-P3 reads.
// Stage->use slack >=3 phases (~2000cy > 900cy HBM); never vmcnt(0) in loop.
template<int OUT_BF16>
__global__ __launch_bounds__(512, 2) void gemm256(
    const u16* __restrict__ A, const u16* __restrict__ B, void* __restrict__ Cout,
    int M, int N, int K, int XC, int SR, int SC) {
  __shared__ u16 As[2][2][64 * 128];   // [parity-buf][128-row half][128x64]
  __shared__ u16 Bs[2][2][64 * 128];
  const int NKT = K >> 6;              // K-tiles of 64 (even, >= 6)
  int bid = (int)blockIdx.x;
  int xcd = bid & 7, l = bid >> 3;     // 2-D XCD sub-grid map
  int tm = (xcd / XC) * SR + l / SC;
  int tn = (xcd % XC) * SC + l % SC;
  int m0 = tm << 8, n0 = tn << 8;
  int t = threadIdx.x;
  int w = t >> 6, lane = t & 63, lo = lane & 15, hi = lane >> 4;
  int wm = w >> 2, wn = w & 3;
  int rbb = (wn & 1) << 6;

  int srow = (w << 3) + (lane >> 3);   // staging row within 64-row group
  int scol = (lane & 7) << 3;          // u16 col base of 16B chunk

  auto stageA = [&](int kt, int buf, int h) {        // one unit = 2 gloads
#pragma unroll
    for (int c2 = 0; c2 < 2; ++c2) {
      int row = (c2 << 6) + srow;
      int col = scol ^ ((row & 7) << 3);             // inverse swizzle on source
      async16(A + (size_t)(m0 + (h << 7) + row) * K + (kt << 6) + col,
              (char*)&As[buf][h][0] + (c2 << 13) + (w << 10));
    }
  };
  auto stageB = [&](int kt, int buf, int h) {
#pragma unroll
    for (int c2 = 0; c2 < 2; ++c2) {
      int row = (c2 << 6) + srow;
      int col = scol ^ ((row & 7) << 3);
      async16(B + (size_t)(n0 + (h << 7) + row) * K + (kt << 6) + col,
              (char*)&Bs[buf][h][0] + (c2 << 13) + (w << 10));
    }
  };

  const f32x4 fz = {0.f, 0.f, 0.f, 0.f};
  f32x4 acc[8][4];
#pragma unroll
  for (int i = 0; i < 8; ++i)
#pragma unroll
    for (int j = 0; j < 4; ++j) acc[i][j] = fz;
  bf16x8 af[4][2], bf0[2][2], bf1[2][2];

  auto rdA = [&](int c, int half, bf16x8 (&dst)[4][2]) {   // 8 x ds_read_b128
    const u16* Ab = &As[c][wm][0];
#pragma unroll
    for (int mf = 0; mf < 4; ++mf)
#pragma unroll
      for (int ks = 0; ks < 2; ++ks) {
        int ra = (half << 6) + (mf << 4) + lo;
        dst[mf][ks] = *(const bf16x8*)(Ab + (ra << 6) +
                      (((ks << 5) + (hi << 3)) ^ ((ra & 7) << 3)));
      }
  };
  auto rdB = [&](int c, int bfrag, bf16x8 (&dst)[2][2]) {  // 4 x ds_read_b128
    const u16* Bb = &Bs[c][wn >> 1][0];
#pragma unroll
    for (int nf = 0; nf < 2; ++nf)
#pragma unroll
      for (int ks = 0; ks < 2; ++ks) {
        int rb = rbb + (bfrag << 5) + (nf << 4) + lo;
        dst[nf][ks] = *(const bf16x8*)(Bb + (rb << 6) +
                      (((ks << 5) + (hi << 3)) ^ ((rb & 7) << 3)));
      }
  };
  auto MM = [&](bf16x8 (&a)[4][2], bf16x8 (&b)[2][2], int mo, int no) {
#pragma unroll
    for (int mf = 0; mf < 4; ++mf)
#pragma unroll
      for (int nf = 0; nf < 2; ++nf)
#pragma unroll
        for (int ks = 0; ks < 2; ++ks)
          acc[mo + mf][no + nf] = mfma16(a[mf][ks], b[nf][ks], acc[mo + mf][no + nf]);
  };

#define BAR()    __builtin_amdgcn_s_barrier()
#define LGKM0()  asm volatile("s_waitcnt lgkmcnt(0)" ::: "memory")
#define VM4()    asm volatile("s_waitcnt vmcnt(4)" ::: "memory")
#define PRIO(x)  __builtin_amdgcn_s_setprio(x)

  // prologue: tile0 full (4 units) + tile1 B (2 units); keep newest 2 units flying
  stageA(0, 0, 0); stageA(0, 0, 1);
  stageB(0, 0, 0); stageB(0, 0, 1);
  stageB(1, 1, 0); stageB(1, 1, 1);
  VM4();
  BAR();

  const int NT = NKT >> 1;
  for (int it = 0; it < NT; ++it) {
    int e = it << 1, o = e + 1;
    int e2 = (e + 2 >= NKT) ? 0 : e + 2;     // wrap (redundant stages, uniform)
    int o2 = (o + 2 >= NKT) ? 1 : o + 2;

    // ---- P1: rd A0(e)+B0(e); stage A(o).h0; MFMA Q00
    rdA(0, 0, af); rdB(0, 0, bf0);
    stageA(o, 1, 0);
    BAR(); LGKM0(); PRIO(1);
    MM(af, bf0, 0, 0);
    PRIO(0); BAR();

    // ---- P2: rd B1(e); stage A(o).h1; MFMA Q01
    rdB(0, 1, bf1);
    stageA(o, 1, 1);
    BAR(); LGKM0(); PRIO(1);
    MM(af, bf1, 0, 2);
    PRIO(0); BAR();

    // ---- P3: rd A1(e); stage B(e+2).h0; MFMA Q11
    rdA(0, 1, af);
    stageB(e2, 0, 0);
    BAR(); LGKM0(); PRIO(1);
    MM(af, bf1, 4, 2);
    PRIO(0); BAR();

    // ---- P4: stage B(e+2).h1; MFMA Q10; vmcnt(4)
    stageB(e2, 0, 1);
    BAR(); PRIO(1);
    MM(af, bf0, 4, 0);
    PRIO(0); VM4(); BAR();

    // ---- P5: rd A0(o)+B0(o); stage A(e+2).h0; MFMA Q00
    rdA(1, 0, af); rdB(1, 0, bf0);
    stageA(e2, 0, 0);
    BAR(); LGKM0(); PRIO(1);
    MM(af, bf0, 0, 0);
    PRIO(0); BAR();

    // ---- P6: rd B1(o); stage A(e+2).h1; MFMA Q01
    rdB(1, 1, bf1);
    stageA(e2, 0, 1);
    BAR(); LGKM0(); PRIO(1);
    MM(af, bf1, 0, 2);
    PRIO(0); BAR();

    // ---- P7: rd A1(o); stage B(o+2).h0; MFMA Q11
    rdA(1, 1, af);
    stageB(o2, 1, 0);
    BAR(); LGKM0(); PRIO(1);
    MM(af, bf1, 4, 2);
    PRIO(0); BAR();

    // ---- P8: stage B(o+2).h1; MFMA Q10; vmcnt(4)
    stageB(o2, 1, 1);
    BAR(); PRIO(1);
    MM(af, bf0, 4, 0);
    PRIO(0); VM4(); BAR();
  }

#undef BAR
#undef LGKM0
#undef VM4
#undef PRIO

  // epilogue
#pragma unroll
  for (int mf = 0; mf < 8; ++mf)
#pragma unroll
    for (int nf = 0; nf < 4; ++nf)
#pragma unroll
      for (int r = 0; r < 4; ++r) {
        int row = m0 + (wm << 7) + (mf << 4) + (hi << 2) + r;
        int col = n0 + (wn << 6) + (nf << 4) + lo;
        if (OUT_BF16) ((u16*)Cout)[(size_t)row * N + col] = f2bf(acc[mf][nf][r]);
        else          ((float*)Cout)[(size_t)row * N + col] = acc[mf][nf][r];
      }
}

// ---------------- RoPE (in-place on bf16, optional output scale) ----------------
__global__ __launch_bounds__(256) void rope_kernel(u16* __restrict__ X,
                                                   const int* __restrict__ pos,
                                                   int ncols, int pitch, float scale) {
  int idx = blockIdx.x * 256 + threadIdx.x;
  int groups = ncols >> 3;
  int m = idx / groups;
  int gi = idx - m * groups;
  if (m >= MROWS) return;
  int head = gi >> 4;
  int d0 = (gi & 15) << 2;
  float p = (float)pos[m];
  u16* base = X + (size_t)m * pitch + head * 128;
  u16 xa[4], xb[4], oa[4], ob[4];
  *(uint2*)xa = *(const uint2*)(base + d0);
  *(uint2*)xb = *(const uint2*)(base + d0 + 64);
#pragma unroll
  for (int i = 0; i < 4; ++i) {
    float j = (float)(d0 + i);
    float inv = __expf(j * -0.14391156516030342f);  // ln(10000)/64
    float fr = p * inv;
    float s, c;
    sincosf(fr, &s, &c);
    float x1 = bf2f(xa[i]), x2 = bf2f(xb[i]);
    oa[i] = f2bf((x1 * c - x2 * s) * scale);
    ob[i] = f2bf((x2 * c + x1 * s) * scale);
  }
  *(uint2*)(base + d0) = *(uint2*)oa;
  *(uint2*)(base + d0 + 64) = *(uint2*)ob;
}

// ---------------- V transpose: QKV[m][5120 + g*128 + d] -> Vt[(b*8+g)*128 + d][s] ----------------
__global__ __launch_bounds__(256) void transpose_v(const u16* __restrict__ V,
                                                   u16* __restrict__ Vt) {
  int bid = blockIdx.x;
  int s0 = (bid & 31) << 6;
  int bg = bid >> 5;
  int b = bg >> 3, g = bg & 7;
  __shared__ u16 tile[64][128];
  int t = threadIdx.x;
#pragma unroll
  for (int r = 0; r < 4; ++r) {
    int c = (r << 8) + t;
    int row = c >> 4, cc = c & 15;
    *(uint4*)&tile[row][cc * 8] =
        *(const uint4*)(V + (size_t)(b * S_LEN + s0 + row) * QKV_N + g * 128 + cc * 8);
  }
  __syncthreads();
#pragma unroll
  for (int r = 0; r < 4; ++r) {
    int c = (r << 8) + t;
    int d = c >> 3, cs = c & 7;
    u16 tmp[8];
#pragma unroll
    for (int i = 0; i < 8; ++i) tmp[i] = tile[cs * 8 + i][d];
    *(uint4*)(Vt + ((size_t)bg * 128 + d) * S_LEN + s0 + cs * 8) = *(uint4*)tmp;
  }
}

// ---------------- Flash attention (causal, GQA 4:1), swapped-operand layout ----------------
__global__ __launch_bounds__(256) void attn_kernel(
    const u16* __restrict__ Q, const u16* __restrict__ K,
    const u16* __restrict__ Vt, u16* __restrict__ O) {
  int bid = blockIdx.x;
  int qt = 31 - (bid >> 6);          // heavy tiles first
  int bh = bid & 63;
  int b = bh >> 5, h = bh & 31;
  int g = h >> 2;
  __shared__ u16 Kl[64 * 128];
  __shared__ u16 Vl[128 * 64];
  __shared__ u16 Pl[4][16 * 72];     // per-wave P^T / O-bounce, pitch 72
  int t = threadIdx.x, w = t >> 6, lane = t & 63, lo = lane & 15, hi = lane >> 4;

  bf16x8 qf[4];   // B-operand: lane -> Q row (q=lo)
  {
    const u16* qb = Q + (size_t)(b * S_LEN + (qt << 6) + (w << 4) + lo) * QKV_N + h * 128;
#pragma unroll
    for (int kk = 0; kk < 4; ++kk) qf[kk] = *(const bf16x8*)(qb + kk * 32 + hi * 8);
  }
  const f32x4 fz = {0.f, 0.f, 0.f, 0.f};
  f32x4 acc[8];
#pragma unroll
  for (int f = 0; f < 8; ++f) acc[f] = fz;
  float mrun = -1e30f, lrun = 0.f;

  const u16* Kbase = K + (size_t)(b * S_LEN) * QKV_N + g * 128;
  const u16* Vbase = Vt + (size_t)((b << 3) + g) * 128 * S_LEN;

  int ntiles = qt + 1;
  for (int tile = 0; tile < ntiles; ++tile) {
    int s0 = tile << 6;
#pragma unroll
    for (int r = 0; r < 4; ++r) {              // stage K tile [64][128], chunk-swizzled
      int c = (r << 8) + (w << 6) + lane;
      int row = c >> 4, cc = c & 15;
      int src = cc ^ (row & 7);
      async16(Kbase + (size_t)(s0 + row) * QKV_N + src * 8,
              (char*)Kl + (r << 12) + (w << 10));
    }
#pragma unroll
    for (int r = 0; r < 4; ++r) {              // stage V^T tile [128][64], chunk-swizzled
      int c = (r << 8) + (w << 6) + lane;
      int row = c >> 3, cc = c & 7;
      int src = cc ^ (row & 7);
      async16(Vbase + (size_t)row * S_LEN + s0 + src * 8,
              (char*)Vl + (r << 12) + (w << 10));
    }
    __syncthreads();

    f32x4 sf[4];
#pragma unroll
    for (int j = 0; j < 4; ++j) {
      f32x4 sv = fz;
#pragma unroll
      for (int kk = 0; kk < 4; ++kk) {
        int row = (j << 4) + lo;
        int ch = ((kk << 2) + hi) ^ (row & 7);
        bf16x8 kf = *(const bf16x8*)(Kl + row * 128 + ch * 8);
        sv = __builtin_amdgcn_mfma_f32_16x16x32_bf16(kf, qf[kk], sv, 0, 0, 0);
      }
      sf[j] = sv;
    }
    if (tile == qt) {                           // causal mask on diagonal tile
      int q_rel = (w << 4) + lo;
#pragma unroll
      for (int j = 0; j < 4; ++j)
#pragma unroll
        for (int r = 0; r < 4; ++r)
          if (((j << 4) + (hi << 2) + r) > q_rel) sf[j][r] = -1e9f;
    }
    float pmax = sf[0][0];
#pragma unroll
    for (int j = 0; j < 4; ++j)
#pragma unroll
      for (int r = 0; r < 4; ++r) pmax = fmaxf(pmax, sf[j][r]);
    pmax = fmaxf(pmax, __shfl_xor(pmax, 16, 64));
    pmax = fmaxf(pmax, __shfl_xor(pmax, 32, 64));
    if (__any(pmax > mrun + 8.f)) {             // defer-max rescale (THR=8)
      float mn = fmaxf(mrun, pmax);
      float fsc = __expf(mrun - mn);
      mrun = mn;
      lrun *= fsc;
#pragma unroll
      for (int f = 0; f < 8; ++f)
#pragma unroll
        for (int r = 0; r < 4; ++r) acc[f][r] *= fsc;
    }
    float psum = 0.f;
#pragma unroll
    for (int j = 0; j < 4; ++j)
#pragma unroll
      for (int r = 0; r < 4; ++r) {
        float p = __expf(sf[j][r] - mrun);
        sf[j][r] = p;
        psum += p;
      }
    psum += __shfl_xor(psum, 16, 64);
    psum += __shfl_xor(psum, 32, 64);
    lrun += psum;

#pragma unroll
    for (int j = 0; j < 4; ++j) {
      uint2 pk;
      pk.x = cvtpk(sf[j][0], sf[j][1]);
      pk.y = cvtpk(sf[j][2], sf[j][3]);
      *(uint2*)&Pl[w][lo * 72 + (j << 4) + (hi << 2)] = pk;
    }
#pragma unroll
    for (int kk = 0; kk < 2; ++kk) {
      bf16x8 pf = *(const bf16x8*)&Pl[w][lo * 72 + (kk << 5) + (hi << 3)];
#pragma unroll
      for (int f = 0; f < 8; ++f) {
        int vrow = (f << 4) + lo;
        int phys = ((kk << 2) + hi) ^ (vrow & 7);
        bf16x8 vf = *(const bf16x8*)(Vl + vrow * 64 + phys * 8);
        acc[f] = __builtin_amdgcn_mfma_f32_16x16x32_bf16(vf, pf, acc[f], 0, 0, 0);
      }
    }
    __syncthreads();
  }

  float rl = 1.0f / lrun;
#pragma unroll
  for (int half = 0; half < 2; ++half) {
#pragma unroll
    for (int f2 = 0; f2 < 4; ++f2) {
      int f = (half << 2) + f2;
      uint2 pk;
      pk.x = cvtpk(acc[f][0] * rl, acc[f][1] * rl);
      pk.y = cvtpk(acc[f][2] * rl, acc[f][3] * rl);
      *(uint2*)&Pl[w][lo * 72 + (f2 << 4) + (hi << 2)] = pk;
    }
#pragma unroll
    for (int it = 0; it < 2; ++it) {
      int rowq = (lane >> 3) + (it << 3);
      int c8 = lane & 7;
      uint4 val = *(const uint4*)&Pl[w][rowq * 72 + c8 * 8];
      *(uint4*)(O + (size_t)(b * S_LEN + (qt << 6) + (w << 4) + rowq) * 4096 +
                h * 128 + (half << 6) + c8 * 8) = val;
    }
  }
}

// ---------------- launch ----------------
extern "C" void kernel_launch(void* const* d_in, const int* in_sizes, int n_in,
                              void* d_out, int out_size, void* d_ws, size_t ws_size,
                              hipStream_t stream) {
  const float* hidden = (const float*)d_in[0];
  const int* pos = (const int*)d_in[1];
  const float* Wq = (const float*)d_in[2];
  const float* Wk = (const float*)d_in[3];
  const float* Wv = (const float*)d_in[4];
  const float* Wo = (const float*)d_in[5];
  float* out = (float*)d_out;

  u16* hb   = (u16*)d_ws;                 // [4096][4096]
  u16* wqb  = hb   + 16777216;            // [4096][4096]  } contiguous -> fused
  u16* wkb  = wqb  + 16777216;            // [1024][4096]  }   B matrix [6144][4096]
  u16* wvb  = wkb  + 4194304;             // [1024][4096]  }
  u16* wob  = wvb  + 4194304;             // [4096][4096]
  u16* QKVb = wob  + 16777216;            // [4096][6144]
  u16* Vtb  = QKVb + 25165824;            // [16*128][2048]
  u16* Ob   = Vtb  + 4194304;             // [4096][4096]

  cvt_f32_bf16<<<8192, 256, 0, stream>>>(hidden, hb, 16777216);
  cvt_f32_bf16<<<8192, 256, 0, stream>>>(Wq, wqb, 16777216);
  cvt_f32_bf16<<<2048, 256, 0, stream>>>(Wk, wkb, 4194304);
  cvt_f32_bf16<<<2048, 256, 0, stream>>>(Wv, wvb, 4194304);
  cvt_f32_bf16<<<8192, 256, 0, stream>>>(Wo, wob, 16777216);

  // QKV: 16x24 tiles = 384 blocks; XCD-grid 2x4, sub 8x6 (XC=4,SR=8,SC=6)
  gemm256<1><<<384, 512, 0, stream>>>(hb, wqb, QKVb, 4096, QKV_N, 4096, 4, 8, 6);

  rope_kernel<<<8192, 256, 0, stream>>>(QKVb, pos, 4096, QKV_N, 0.08838834764831845f); // Q (pre-scaled)
  rope_kernel<<<2048, 256, 0, stream>>>(QKVb + 4096, pos, 1024, QKV_N, 1.0f);          // K

  transpose_v<<<512, 256, 0, stream>>>(QKVb + 5120, Vtb);

  attn_kernel<<<2048, 256, 0, stream>>>(QKVb, QKVb + 4096, Vtb, Ob);

  // O-proj: 16x16 tiles = 256 blocks; XCD-grid 4x2, sub 4x8 (XC=2,SR=4,SC=8)
  gemm256<0><<<256, 512, 0, stream>>>(Ob, wob, out, 4096, 4096, 4096, 2, 4, 8);
}